// Round 7
// baseline (5802.101 us; speedup 1.0000x reference)
//
#include <hip/hip_runtime.h>
#include <math.h>

#define H 300
#define H3 900
#define NAt 16385
#define NBd 65537
#define NM 256
#define APM 64

typedef __attribute__((ext_vector_type(8))) short bf16x8;
typedef __attribute__((ext_vector_type(4))) float f32x4;

__device__ __forceinline__ unsigned bf16_rne(float x) {
  unsigned u = __float_as_uint(x);
  return (u + 0x7fffu + ((u >> 16) & 1u)) >> 16;
}
__device__ __forceinline__ float bf16_up(unsigned h) {
  return __uint_as_float(h << 16);
}
// 3-way split: x ~= h + m + l (each bf16), residual ~2^-26 |x|
__device__ __forceinline__ void split3(float x, unsigned &h, unsigned &m, unsigned &l) {
  h = bf16_rne(x);
  float r1 = x - bf16_up(h);
  m = bf16_rne(r1);
  float r2 = r1 - bf16_up(m);
  l = bf16_rne(r2);
}
__device__ __forceinline__ void pack8(const unsigned* v, uint4 &o) {
  o.x = v[0] | (v[1] << 16); o.y = v[2] | (v[3] << 16);
  o.z = v[4] | (v[5] << 16); o.w = v[6] | (v[7] << 16);
}

// ======================= weight pre-split =======================
// B_logical[K][N] -> 3 bf16 planes in MFMA fragment-granule order.
// granule g = (kt*NT + t)*64 + lane holds n = t*16+(lane&15),
// k = kt*32 + (lane>>4)*8 + j. plane p at offset p*KT*NT*64.
// TRANS: B_logical[k][n] = W[n][k].
template<bool TRANS>
__global__ __launch_bounds__(256) void prep_split_kernel(
    const float* __restrict__ B, uint4* __restrict__ out,
    int K, int N, int ldb, int KT, int NT)
{
  int g = blockIdx.x * 256 + threadIdx.x;
  int total = KT * NT * 64;
  if (g >= total) return;
  int lane = g & 63;
  int t = (g >> 6) % NT;
  int kt = (g >> 6) / NT;
  int n = t * 16 + (lane & 15);
  int kb = kt * 32 + ((lane >> 4) << 3);
  float x[8];
#pragma unroll
  for (int j = 0; j < 8; j++) {
    int gk = kb + j;
    float v = 0.f;
    if (n < N && gk < K)
      v = TRANS ? B[(size_t)n * ldb + gk] : B[(size_t)gk * ldb + n];
    x[j] = v;
  }
  unsigned h[8], m[8], l[8];
#pragma unroll
  for (int j = 0; j < 8; j++) split3(x[j], h[j], m[j], l[j]);
  uint4 hv, mv, lv;
  pack8(h, hv); pack8(m, mv); pack8(l, lv);
  out[g] = hv;
  out[total + g] = mv;
  out[2 * total + g] = lv;
}

// ============== split-bf16 MFMA GEMM v4: pre-split B, 2-deep A prefetch ==============
// BM=64, BN=320. 4 waves: wave w owns n-tiles [5w,5w+5), all 4 m-tiles.
// B fragments global->VGPR from pre-split planes. A staged via 2-register-set
// + 2-LDS-buffer pipeline: load(kt+2) issued at top of iter kt.
template<bool ADDMAT, bool BIAS, bool RELU, bool GATHER, bool CONCAT, bool W2>
__global__ __launch_bounds__(256, 4) void gemm_mfma3(
    const float* __restrict__ A, const float* __restrict__ A2,
    const float* __restrict__ A3,
    const int* __restrict__ idx1, const int* __restrict__ idx2,
    const uint4* __restrict__ Bs,
    float* __restrict__ C, float* __restrict__ C2,
    const float* __restrict__ D, const float* __restrict__ bias,
    int M, int N, int K, int lda, int ldc, int KT, int NT)
{
  __shared__ uint4 sA[2][3][256];
  const int tid = threadIdx.x;
  const int lane = tid & 63;
  const int wid = tid >> 6;
  const int m0 = blockIdx.y * 64;
  const int tb = blockIdx.x * 20;
  int NTloc = NT - tb;
  if (NTloc > 20) NTloc = 20;

  const int a_row = m0 + (wid << 4) + (lane & 15);
  const int a_koct = lane >> 4;
  const bool arok = a_row < M;
  const float* Ap = nullptr;
  const float* Ap2 = nullptr;
  const float* Ap3 = nullptr;
  if constexpr (GATHER) {
    int i1 = arok ? idx1[a_row] : 0;
    int i2 = arok ? idx2[a_row] : 0;
    Ap  = A  + (size_t)i1 * lda;
    Ap2 = A2 + (size_t)i2 * lda;
  } else if constexpr (CONCAT) {
    int r = arok ? a_row : 0;
    Ap  = A  + (size_t)r * lda;
    Ap2 = A2 + (size_t)r * lda;
    Ap3 = A3 + (size_t)r * lda;
  } else {
    Ap = A + (size_t)(arok ? a_row : 0) * lda;
  }

  const int PS = KT * NT * 64;  // plane stride (uint4 units)

  f32x4 acc[4][5];
#pragma unroll
  for (int i = 0; i < 4; i++)
#pragma unroll
    for (int j = 0; j < 5; j++) acc[i][j] = (f32x4){0.f, 0.f, 0.f, 0.f};

  auto loadA = [&](float* dst, int kt_) {
#pragma unroll
    for (int j = 0; j < 8; j++) {
      int gk = (kt_ << 5) + (a_koct << 3) + j;
      float v = 0.f;
      if (arok && gk < K) {
        if constexpr (GATHER) {
          v = Ap[gk] - Ap2[gk];
        } else if constexpr (CONCAT) {
          int s_ = (gk >= 2 * lda) ? 2 : ((gk >= lda) ? 1 : 0);
          int col = gk - s_ * lda;
          const float* src = (s_ == 0) ? Ap : ((s_ == 1) ? Ap2 : Ap3);
          v = src[col];
        } else {
          v = Ap[gk];
        }
      }
      dst[j] = v;
    }
  };
  auto writeA = [&](const float* src, int slot) {
    unsigned h[8], m[8], l[8];
#pragma unroll
    for (int j = 0; j < 8; j++) split3(src[j], h[j], m[j], l[j]);
    uint4 hv, mv, lv;
    pack8(h, hv); pack8(m, mv); pack8(l, lv);
    const int fi = (wid << 6) | lane;
    sA[slot][0][fi] = hv; sA[slot][1][fi] = mv; sA[slot][2][fi] = lv;
  };

  float ax0[8], ax1[8];
  loadA(ax0, 0);
  writeA(ax0, 0);
  if (KT > 1) loadA(ax0, 1);   // ax0 now holds kt=1 data
  __syncthreads();

  for (int kt = 0; kt < KT; kt++) {
    const int cur = kt & 1;
    const bool more = kt + 1 < KT;
    float* axN = (kt & 1) ? ax1 : ax0;   // holds kt+1 data (loaded earlier)
    float* axP = (kt & 1) ? ax0 : ax1;   // free: receives kt+2 load
    if (kt + 2 < KT) loadA(axP, kt + 2);

    bf16x8 aF[3][4];
#pragma unroll
    for (int p = 0; p < 3; p++)
#pragma unroll
      for (int i = 0; i < 4; i++)
        aF[p][i] = ((const bf16x8*)sA[cur][p])[(i << 6) | lane];
    const int bk = kt * NT * 64 + lane;
#pragma unroll
    for (int j = 0; j < 5; j++) {
      const int t = wid * 5 + j;
      if (t < NTloc) {
        const int gidx = bk + (tb + t) * 64;
        bf16x8 b0 = ((const bf16x8*)Bs)[gidx];
        bf16x8 b1 = ((const bf16x8*)Bs)[gidx + PS];
        bf16x8 b2 = ((const bf16x8*)Bs)[gidx + 2 * PS];
#pragma unroll
        for (int i = 0; i < 4; i++) {
          acc[i][j] = __builtin_amdgcn_mfma_f32_16x16x32_bf16(aF[2][i], b0, acc[i][j], 0, 0, 0);
          acc[i][j] = __builtin_amdgcn_mfma_f32_16x16x32_bf16(aF[0][i], b2, acc[i][j], 0, 0, 0);
          acc[i][j] = __builtin_amdgcn_mfma_f32_16x16x32_bf16(aF[1][i], b1, acc[i][j], 0, 0, 0);
          acc[i][j] = __builtin_amdgcn_mfma_f32_16x16x32_bf16(aF[1][i], b0, acc[i][j], 0, 0, 0);
          acc[i][j] = __builtin_amdgcn_mfma_f32_16x16x32_bf16(aF[0][i], b1, acc[i][j], 0, 0, 0);
          acc[i][j] = __builtin_amdgcn_mfma_f32_16x16x32_bf16(aF[0][i], b0, acc[i][j], 0, 0, 0);
        }
      }
    }
    if (more) writeA(axN, cur ^ 1);
    __syncthreads();
  }

  // epilogue: C/D layout col=lane&15, row=(lane>>4)*4+r
  const int cr = (lane >> 4) << 2;
  const int cc = lane & 15;
#pragma unroll
  for (int j = 0; j < 5; j++) {
    const int t = wid * 5 + j;
    if (t >= NTloc) break;
    const int gn = ((tb + t) << 4) + cc;
    if (gn >= N) continue;
#pragma unroll
    for (int i = 0; i < 4; i++) {
#pragma unroll
      for (int r = 0; r < 4; r++) {
        const int gm = m0 + (i << 4) + cr + r;
        if (gm >= M) continue;
        const size_t rowoff = (size_t)gm * ldc;
        float v = acc[i][j][r];
        if constexpr (ADDMAT) v += D[rowoff + gn];
        if constexpr (BIAS) v += bias[gn];
        if constexpr (RELU) v = fmaxf(v, 0.f);
        C[rowoff + gn] = v;
        if constexpr (W2) C2[rowoff + gn] = v;
      }
    }
  }
}

// ============== neighbor aggregation (float4): sum * max over 6 ==============
template<bool UPDATE>
__global__ __launch_bounds__(256) void agg_kernel(
    const float* __restrict__ message_bond, const int* __restrict__ a2b,
    float* __restrict__ out)
{
  int gid = blockIdx.x * 256 + threadIdx.x;
  if (gid >= NAt * 75) return;
  int a = gid / 75;
  int c4 = gid - a * 75;
  const int* ab = a2b + (size_t)a * 6;
  float4 s = {0.f, 0.f, 0.f, 0.f};
  float4 mx = {-3.0e38f, -3.0e38f, -3.0e38f, -3.0e38f};
#pragma unroll
  for (int j = 0; j < 6; j++) {
    float4 v = *(const float4*)(message_bond + (size_t)ab[j] * H + c4 * 4);
    s.x += v.x; s.y += v.y; s.z += v.z; s.w += v.w;
    mx.x = fmaxf(mx.x, v.x); mx.y = fmaxf(mx.y, v.y);
    mx.z = fmaxf(mx.z, v.z); mx.w = fmaxf(mx.w, v.w);
  }
  float4* o = (float4*)(out + (size_t)a * H + c4 * 4);
  float4 r;
  r.x = s.x * mx.x; r.y = s.y * mx.y; r.z = s.z * mx.z; r.w = s.w * mx.w;
  if (UPDATE) {
    float4 c = *o;
    r.x += c.x; r.y += c.y; r.z += c.z; r.w += c.w;
  }
  *o = r;
}

// ======================= misc elementwise =======================
__global__ __launch_bounds__(256) void msg_kernel(
    const float* __restrict__ node, const float* __restrict__ gru_bias,
    float* __restrict__ msg)
{
  int gid = blockIdx.x * 256 + threadIdx.x;
  if (gid >= NAt * H) return;
  int hh = gid % H;
  msg[gid] = fmaxf(node[gid] + gru_bias[hh], 0.f);
}

__global__ __launch_bounds__(256) void h0_kernel(
    const float* __restrict__ node, float* __restrict__ h0)
{
  int gid = blockIdx.x * 256 + threadIdx.x;
  if (gid >= NM * H) return;
  int m = gid / H;
  int hh = gid - m * H;
  const float* base = node + ((size_t)(1 + m * APM)) * H + hh;
  float mx = base[0];
  for (int t = 1; t < APM; t++) mx = fmaxf(mx, base[(size_t)t * H]);
  h0[gid] = mx;
}

__global__ __launch_bounds__(256) void row0_kernel(
    const float* __restrict__ msg, float* __restrict__ message)
{
  int gid = blockIdx.x * 256 + threadIdx.x;
  if (gid >= 2 * H) return;
  message[gid] = msg[gid % H];
}

__global__ __launch_bounds__(256) void mean_kernel(
    const float* __restrict__ ah, float* __restrict__ out)
{
  int gid = blockIdx.x * 256 + threadIdx.x;
  if (gid >= NM * H) return;
  int m = gid / H;
  int hh = gid - m * H;
  const float* base = ah + ((size_t)(1 + m * APM)) * H + hh;
  float s = 0.f;
#pragma unroll 8
  for (int t = 0; t < APM; t++) s += base[(size_t)t * H];
  out[gid] = s * (1.f / APM);
}

// ======================= GRU step =======================
__global__ __launch_bounds__(256) void gru_step_kernel(
    const float* __restrict__ xg_f, const float* __restrict__ xg_b,
    const float* __restrict__ w_hh_f, const float* __restrict__ w_hh_b,
    const float* __restrict__ b_hh_f, const float* __restrict__ b_hh_b,
    const float* __restrict__ h0,
    float* __restrict__ h_buf,   // [2][2][NM][H]
    float* __restrict__ g_buf,   // [2][2][NM][H3]
    float* __restrict__ message, // [NAt][600]
    int s)
{
  __shared__ float h_lds[8 * H];
  const int tid = threadIdx.x;
  const int b = blockIdx.x;
  const int ct = b & 3;
  const int mg = (b >> 2) & 31;
  const int dir = b >> 7;
  const int r = s & 1;
  const int w = 1 - r;
  const float* xg = dir ? xg_b : xg_f;
  const float* whh = dir ? w_hh_b : w_hh_f;
  const float* bhh = dir ? b_hh_b : b_hh_f;
  const float* hb_r = h_buf + ((size_t)(r * 2 + dir)) * NM * H;
  float* hb_w = h_buf + ((size_t)(w * 2 + dir)) * NM * H;
  const float* gb_r = g_buf + ((size_t)(r * 2 + dir)) * NM * H3;
  float* gb_w = g_buf + ((size_t)(w * 2 + dir)) * NM * H3;

  int t_prev = 0;
  if (s > 0) t_prev = dir ? (64 - s) : (s - 1);

  // phase 1: h_cur for this block's 8 mols
  for (int i = tid; i < 8 * H; i += 256) {
    int m = i / H;
    int hh = i - m * H;
    int mol = mg * 8 + m;
    float hc;
    if (s == 0) {
      hc = h0[(size_t)mol * H + hh];
    } else {
      const float* xr = xg + ((size_t)(mol * 64 + t_prev)) * H3;
      float ir = xr[hh], iz = xr[H + hh], inn = xr[2 * H + hh];
      const float* gp = gb_r + (size_t)mol * H3;
      float hr = gp[hh], hz = gp[H + hh], hn = gp[2 * H + hh];
      float hp = hb_r[(size_t)mol * H + hh];
      float rr = 1.f / (1.f + expf(-(ir + hr)));
      float zz = 1.f / (1.f + expf(-(iz + hz)));
      float nn = tanhf(inn + rr * hn);
      hc = (1.f - zz) * nn + zz * hp;
    }
    h_lds[i] = hc;
    if (ct == 0) {
      hb_w[(size_t)mol * H + hh] = hc;
      if (s > 0) {
        int row = 1 + mol * 64 + t_prev;
        message[(size_t)row * 600 + dir * H + hh] = hc;
      }
    }
  }
  __syncthreads();
  if (s >= 64) return;

  // phase 2: gate slice [ct*225,(ct+1)*225), 2-way ILP
  for (int base = tid; base < 8 * 225; base += 512) {
    const int iA = base;
    const int iB = base + 256;
    const bool hasB = iB < 8 * 225;
    const int mA = iA & 7;
    const int gA = ct * 225 + (iA >> 3);
    const int mB = hasB ? (iB & 7) : mA;
    const int gB = hasB ? (ct * 225 + (iB >> 3)) : gA;
    const float4* wA = (const float4*)(whh + (size_t)gA * H);
    const float4* wB = (const float4*)(whh + (size_t)gB * H);
    const float4* hA = (const float4*)(h_lds + mA * H);
    const float4* hB = (const float4*)(h_lds + mB * H);
    float accA = bhh[gA];
    float accB = hasB ? bhh[gB] : 0.f;
#pragma unroll 5
    for (int k = 0; k < H / 4; k++) {
      float4 wa = wA[k], ha = hA[k];
      float4 wb = wB[k], hb = hB[k];
      accA += wa.x * ha.x + wa.y * ha.y + wa.z * ha.z + wa.w * ha.w;
      accB += wb.x * hb.x + wb.y * hb.y + wb.z * hb.z + wb.w * hb.w;
    }
    gb_w[(size_t)(mg * 8 + mA) * H3 + gA] = accA;
    if (hasB) gb_w[(size_t)(mg * 8 + mB) * H3 + gB] = accB;
  }
}

// ======================= host =======================
// Base layout 63,898,800 floats = 255.6 MB + pre-split weights 9.2 MB at tail
// (ws_size verified sufficient in round 6: presplit path ran).
extern "C" void kernel_launch(void* const* d_in, const int* in_sizes, int n_in,
                              void* d_out, int out_size, void* d_ws, size_t ws_size,
                              hipStream_t stream) {
  (void)in_sizes; (void)n_in; (void)out_size; (void)ws_size;
  const float* f_atoms  = (const float*)d_in[0];
  const float* f_bonds  = (const float*)d_in[1];
  const int*   a2b      = (const int*)d_in[2];
  const int*   b2a      = (const int*)d_in[3];
  const int*   b2revb   = (const int*)d_in[4];
  const float* W_i_atom = (const float*)d_in[5];
  const float* W_i_bond = (const float*)d_in[6];
  const float* W_h      = (const float*)d_in[7];
  const float* W_lr     = (const float*)d_in[8];
  const float* W_o      = (const float*)d_in[9];
  const float* b_o      = (const float*)d_in[10];
  const float* gru_bias = (const float*)d_in[11];
  const float* w_ih_f   = (const float*)d_in[12];
  const float* w_hh_f   = (const float*)d_in[13];
  const float* b_ih_f   = (const float*)d_in[14];
  const float* b_hh_f   = (const float*)d_in[15];
  const float* w_ih_b   = (const float*)d_in[16];
  const float* w_hh_b   = (const float*)d_in[17];
  const float* b_ih_b   = (const float*)d_in[18];
  const float* b_hh_b   = (const float*)d_in[19];

  float* ws = (float*)d_ws;
  const size_t SZ_B = (size_t)NBd * H;  // 19,661,100
  const size_t SZ_A = (size_t)NAt * H;  //  4,915,500

  float* ib  = ws;
  float* mb0 = ws + SZ_B;
  float* mb1 = ws + 2 * SZ_B;
  float* ma  = ws + 3 * SZ_B;
  float* xgf     = ib;
  float* message = mb0;
  float* h0      = mb0 + 9831000;
  float* hbuf    = h0 + (size_t)NM * H + 2 * (size_t)H * H3;  // keep r6 offsets
  float* gbuf    = hbuf + (size_t)4 * NM * H;
  float* aggb    = mb1;
  float* node    = mb1 + SZ_A;
  float* iat     = mb1 + 2 * SZ_A;
  float* msg     = mb1 + 14745600;
  float* xgb     = mb1;
  float* ah      = ma;

  // pre-split weight region at tail (uint4 granule counts)
  const size_t BASE_FLOATS = 63898800;
  uint4* wsp = (uint4*)(ws + BASE_FLOATS);
  const int G_IA = 5 * 19 * 64;
  const int G_IB = 5 * 19 * 64;
  const int G_WH = 10 * 19 * 64;
  const int G_LR = 29 * 19 * 64;
  const int G_WT = 10 * 57 * 64;
  const int G_WO = 19 * 19 * 64;
  uint4* sp_ia = wsp;
  uint4* sp_ib = sp_ia + 3 * G_IA;
  uint4* sp_wh = sp_ib + 3 * G_IB;
  uint4* sp_lr = sp_wh + 4 * 3 * G_WH;
  uint4* sp_tf = sp_lr + 3 * G_LR;
  uint4* sp_tb = sp_tf + 3 * G_WT;
  uint4* sp_wo = sp_tb + 3 * G_WT;

  dim3 blk(256);
  auto gg3 = [](int M, int NT) {
    return dim3((unsigned)((NT + 19) / 20), (unsigned)((M + 63) / 64));
  };
  auto pg = [](int gran) { return dim3((unsigned)((gran + 255) / 256)); };
  const int gA4 = (int)((NAt * 75 + 255) / 256);
  const int gAe = (int)((SZ_A + 255) / 256);

  // ---- weight prep ----
  prep_split_kernel<false><<<pg(G_IA), blk, 0, stream>>>(W_i_atom, sp_ia, 133, 300, 300, 5, 19);
  prep_split_kernel<false><<<pg(G_IB), blk, 0, stream>>>(W_i_bond, sp_ib, 147, 300, 300, 5, 19);
  for (int d = 0; d < 4; d++)
    prep_split_kernel<false><<<pg(G_WH), blk, 0, stream>>>(
        W_h + (size_t)d * H * H, sp_wh + (size_t)d * 3 * G_WH, 300, 300, 300, 10, 19);
  prep_split_kernel<false><<<pg(G_LR), blk, 0, stream>>>(W_lr, sp_lr, 900, 300, 300, 29, 19);
  prep_split_kernel<true><<<pg(G_WT), blk, 0, stream>>>(w_ih_f, sp_tf, 300, 900, 300, 10, 57);
  prep_split_kernel<true><<<pg(G_WT), blk, 0, stream>>>(w_ih_b, sp_tb, 300, 900, 300, 10, 57);
  prep_split_kernel<false><<<pg(G_WO), blk, 0, stream>>>(W_o, sp_wo, 600, 300, 300, 19, 19);

  // ma = relu(f_atoms @ W_i_atom)
  gemm_mfma3<false,false,true,false,false,false><<<gg3(NAt, 19), blk, 0, stream>>>(
      f_atoms, nullptr, nullptr, nullptr, nullptr, sp_ia, ma, nullptr, nullptr, nullptr,
      NAt, H, 133, 133, H, 5, 19);
  // ib = relu(f_bonds @ W_i_bond); mb0 = copy
  gemm_mfma3<false,false,true,false,false,true><<<gg3(NBd, 19), blk, 0, stream>>>(
      f_bonds, nullptr, nullptr, nullptr, nullptr, sp_ib, ib, mb0, nullptr, nullptr,
      NBd, H, 147, 147, H, 5, 19);

  float* mbp[2] = {mb0, mb1};
  int cur = 0;
  for (int d = 0; d < 4; d++) {
    agg_kernel<true><<<gA4, blk, 0, stream>>>(mbp[cur], a2b, ma);
    gemm_mfma3<true,false,true,true,false,false><<<gg3(NBd, 19), blk, 0, stream>>>(
        ma, mbp[cur], nullptr, b2a, b2revb, sp_wh + (size_t)d * 3 * G_WH,
        mbp[1 - cur], nullptr, ib, nullptr, NBd, H, H, H, H, 10, 19);
    cur ^= 1;
  }
  agg_kernel<false><<<gA4, blk, 0, stream>>>(mb0, a2b, aggb);

  gemm_mfma3<false,false,true,false,false,false><<<gg3(NAt, 19), blk, 0, stream>>>(
      f_atoms, nullptr, nullptr, nullptr, nullptr, sp_ia, iat, nullptr, nullptr, nullptr,
      NAt, H, 133, 133, H, 5, 19);
  gemm_mfma3<false,false,false,false,true,false><<<gg3(NAt, 19), blk, 0, stream>>>(
      aggb, ma, iat, nullptr, nullptr, sp_lr, node, nullptr, nullptr, nullptr,
      NAt, H, 900, H, H, 29, 19);

  h0_kernel<<<(NM * H + 255) / 256, blk, 0, stream>>>(node, h0);
  msg_kernel<<<gAe, blk, 0, stream>>>(node, gru_bias, msg);

  gemm_mfma3<false,true,false,false,false,false><<<gg3(16384, 57), blk, 0, stream>>>(
      msg + H, nullptr, nullptr, nullptr, nullptr, sp_tf, xgf, nullptr, nullptr, b_ih_f,
      16384, H3, H, H, H3, 10, 57);
  gemm_mfma3<false,true,false,false,false,false><<<gg3(16384, 57), blk, 0, stream>>>(
      msg + H, nullptr, nullptr, nullptr, nullptr, sp_tb, xgb, nullptr, nullptr, b_ih_b,
      16384, H3, H, H, H3, 10, 57);

  for (int s = 0; s <= 64; s++) {
    gru_step_kernel<<<256, blk, 0, stream>>>(
        xgf, xgb, w_hh_f, w_hh_b, b_hh_f, b_hh_b, h0, hbuf, gbuf, message, s);
  }
  row0_kernel<<<3, blk, 0, stream>>>(msg, message);

  gemm_mfma3<false,true,true,false,false,false><<<gg3(NAt, 19), blk, 0, stream>>>(
      message, nullptr, nullptr, nullptr, nullptr, sp_wo, ah, nullptr, nullptr, b_o,
      NAt, H, 600, 600, H, 19, 19);
  mean_kernel<<<(NM * H + 255) / 256, blk, 0, stream>>>(ah, (float*)d_out);
}

// Round 8
// 3623.079 us; speedup vs baseline: 1.6014x; 1.6014x over previous
//
#include <hip/hip_runtime.h>
#include <math.h>

#define H 300
#define H3 900
#define NAt 16385
#define NBd 65537
#define NM 256
#define APM 64

typedef __attribute__((ext_vector_type(8))) short bf16x8;
typedef __attribute__((ext_vector_type(4))) float f32x4;

__device__ __forceinline__ unsigned bf16_rne(float x) {
  unsigned u = __float_as_uint(x);
  return (u + 0x7fffu + ((u >> 16) & 1u)) >> 16;
}
__device__ __forceinline__ float bf16_up(unsigned h) {
  return __uint_as_float(h << 16);
}
// 3-way split: x ~= h + m + l (each bf16), residual ~2^-26 |x|
__device__ __forceinline__ void split3(float x, unsigned &h, unsigned &m, unsigned &l) {
  h = bf16_rne(x);
  float r1 = x - bf16_up(h);
  m = bf16_rne(r1);
  float r2 = r1 - bf16_up(m);
  l = bf16_rne(r2);
}
__device__ __forceinline__ void pack8(const unsigned* v, uint4 &o) {
  o.x = v[0] | (v[1] << 16); o.y = v[2] | (v[3] << 16);
  o.z = v[4] | (v[5] << 16); o.w = v[6] | (v[7] << 16);
}

// ======================= weight pre-split =======================
// B_logical[K][N] -> 3 bf16 planes in MFMA fragment-granule order.
// granule g = (kt*NT + t)*64 + lane holds n = t*16+(lane&15),
// k = kt*32 + (lane>>4)*8 + j. plane p at offset p*KT*NT*64.
// TRANS: B_logical[k][n] = W[n][k].
template<bool TRANS>
__global__ __launch_bounds__(256) void prep_split_kernel(
    const float* __restrict__ B, uint4* __restrict__ out,
    int K, int N, int ldb, int KT, int NT)
{
  int g = blockIdx.x * 256 + threadIdx.x;
  int total = KT * NT * 64;
  if (g >= total) return;
  int lane = g & 63;
  int t = (g >> 6) % NT;
  int kt = (g >> 6) / NT;
  int n = t * 16 + (lane & 15);
  int kb = kt * 32 + ((lane >> 4) << 3);
  float x[8];
#pragma unroll
  for (int j = 0; j < 8; j++) {
    int gk = kb + j;
    float v = 0.f;
    if (n < N && gk < K)
      v = TRANS ? B[(size_t)n * ldb + gk] : B[(size_t)gk * ldb + n];
    x[j] = v;
  }
  unsigned h[8], m[8], l[8];
#pragma unroll
  for (int j = 0; j < 8; j++) split3(x[j], h[j], m[j], l[j]);
  uint4 hv, mv, lv;
  pack8(h, hv); pack8(m, mv); pack8(l, lv);
  out[g] = hv;
  out[total + g] = mv;
  out[2 * total + g] = lv;
}

// ============== split-bf16 MFMA GEMM (round-6 structure + dwordx4 A loads) ==============
// BM=64, BN=320. 4 waves: wave w owns n-tiles [5w,5w+5), all 4 m-tiles.
// B fragments global->VGPR from pre-split planes. A staged in 2x-buffered LDS,
// load of kt+1 issued before compute of kt. launch_bounds(256,3): 164 regs/wave
// fits 3 waves/EU WITHOUT spilling (r7 post-mortem: (256,4) spilled acc -> 2.5x slower).
// VEC: A rows are 16B-aligned with lda%4==0 -> 2x global_load_dwordx4 per granule
// (scalar fallback at K-edge granule).
template<bool ADDMAT, bool BIAS, bool RELU, bool GATHER, bool CONCAT, bool W2, bool VEC>
__global__ __launch_bounds__(256, 3) void gemm_mfma3(
    const float* __restrict__ A, const float* __restrict__ A2,
    const float* __restrict__ A3,
    const int* __restrict__ idx1, const int* __restrict__ idx2,
    const uint4* __restrict__ Bs,
    float* __restrict__ C, float* __restrict__ C2,
    const float* __restrict__ D, const float* __restrict__ bias,
    int M, int N, int K, int lda, int ldc, int KT, int NT)
{
  __shared__ uint4 sA[2][3][256];
  const int tid = threadIdx.x;
  const int lane = tid & 63;
  const int wid = tid >> 6;
  const int m0 = blockIdx.y * 64;
  const int tb = blockIdx.x * 20;
  int NTloc = NT - tb;
  if (NTloc > 20) NTloc = 20;

  const int a_row = m0 + (wid << 4) + (lane & 15);
  const int a_koct = lane >> 4;
  const bool arok = a_row < M;
  const float* Ap = nullptr;
  const float* Ap2 = nullptr;
  const float* Ap3 = nullptr;
  if constexpr (GATHER) {
    int i1 = arok ? idx1[a_row] : 0;
    int i2 = arok ? idx2[a_row] : 0;
    Ap  = A  + (size_t)i1 * lda;
    Ap2 = A2 + (size_t)i2 * lda;
  } else if constexpr (CONCAT) {
    int r = arok ? a_row : 0;
    Ap  = A  + (size_t)r * lda;
    Ap2 = A2 + (size_t)r * lda;
    Ap3 = A3 + (size_t)r * lda;
  } else {
    Ap = A + (size_t)(arok ? a_row : 0) * lda;
  }

  const int PS = KT * NT * 64;  // plane stride (uint4 units)

  f32x4 acc[4][5];
#pragma unroll
  for (int i = 0; i < 4; i++)
#pragma unroll
    for (int j = 0; j < 5; j++) acc[i][j] = (f32x4){0.f, 0.f, 0.f, 0.f};

  float ax[8];
  auto loadA = [&](int kt_) {
    const int gk0 = (kt_ << 5) + (a_koct << 3);
    if constexpr (VEC && !CONCAT) {
      if (arok && gk0 + 8 <= K) {
        float4 p0 = *(const float4*)(Ap + gk0);
        float4 p1 = *(const float4*)(Ap + gk0 + 4);
        if constexpr (GATHER) {
          float4 q0 = *(const float4*)(Ap2 + gk0);
          float4 q1 = *(const float4*)(Ap2 + gk0 + 4);
          ax[0] = p0.x - q0.x; ax[1] = p0.y - q0.y;
          ax[2] = p0.z - q0.z; ax[3] = p0.w - q0.w;
          ax[4] = p1.x - q1.x; ax[5] = p1.y - q1.y;
          ax[6] = p1.z - q1.z; ax[7] = p1.w - q1.w;
        } else {
          ax[0] = p0.x; ax[1] = p0.y; ax[2] = p0.z; ax[3] = p0.w;
          ax[4] = p1.x; ax[5] = p1.y; ax[6] = p1.z; ax[7] = p1.w;
        }
        return;
      }
    }
#pragma unroll
    for (int j = 0; j < 8; j++) {
      int gk = gk0 + j;
      float v = 0.f;
      if (arok && gk < K) {
        if constexpr (GATHER) {
          v = Ap[gk] - Ap2[gk];
        } else if constexpr (CONCAT) {
          int s_ = (gk >= 2 * lda) ? 2 : ((gk >= lda) ? 1 : 0);
          int col = gk - s_ * lda;
          const float* src = (s_ == 0) ? Ap : ((s_ == 1) ? Ap2 : Ap3);
          v = src[col];
        } else {
          v = Ap[gk];
        }
      }
      ax[j] = v;
    }
  };
  auto writeA = [&](int slot) {
    unsigned h[8], m[8], l[8];
#pragma unroll
    for (int j = 0; j < 8; j++) split3(ax[j], h[j], m[j], l[j]);
    uint4 hv, mv, lv;
    pack8(h, hv); pack8(m, mv); pack8(l, lv);
    const int fi = (wid << 6) | lane;
    sA[slot][0][fi] = hv; sA[slot][1][fi] = mv; sA[slot][2][fi] = lv;
  };

  loadA(0);
  writeA(0);
  __syncthreads();

  for (int kt = 0; kt < KT; kt++) {
    const int cur = kt & 1;
    const bool more = kt + 1 < KT;
    if (more) loadA(kt + 1);

    bf16x8 aF[3][4];
#pragma unroll
    for (int p = 0; p < 3; p++)
#pragma unroll
      for (int i = 0; i < 4; i++)
        aF[p][i] = ((const bf16x8*)sA[cur][p])[(i << 6) | lane];
    const int bk = kt * NT * 64 + lane;
#pragma unroll
    for (int j = 0; j < 5; j++) {
      const int t = wid * 5 + j;
      if (t < NTloc) {
        const int gidx = bk + (tb + t) * 64;
        bf16x8 b0 = ((const bf16x8*)Bs)[gidx];
        bf16x8 b1 = ((const bf16x8*)Bs)[gidx + PS];
        bf16x8 b2 = ((const bf16x8*)Bs)[gidx + 2 * PS];
#pragma unroll
        for (int i = 0; i < 4; i++) {
          acc[i][j] = __builtin_amdgcn_mfma_f32_16x16x32_bf16(aF[2][i], b0, acc[i][j], 0, 0, 0);
          acc[i][j] = __builtin_amdgcn_mfma_f32_16x16x32_bf16(aF[0][i], b2, acc[i][j], 0, 0, 0);
          acc[i][j] = __builtin_amdgcn_mfma_f32_16x16x32_bf16(aF[1][i], b1, acc[i][j], 0, 0, 0);
          acc[i][j] = __builtin_amdgcn_mfma_f32_16x16x32_bf16(aF[1][i], b0, acc[i][j], 0, 0, 0);
          acc[i][j] = __builtin_amdgcn_mfma_f32_16x16x32_bf16(aF[0][i], b1, acc[i][j], 0, 0, 0);
          acc[i][j] = __builtin_amdgcn_mfma_f32_16x16x32_bf16(aF[0][i], b0, acc[i][j], 0, 0, 0);
        }
      }
    }
    if (more) writeA(cur ^ 1);
    __syncthreads();
  }

  // epilogue: C/D layout col=lane&15, row=(lane>>4)*4+r
  const int cr = (lane >> 4) << 2;
  const int cc = lane & 15;
#pragma unroll
  for (int j = 0; j < 5; j++) {
    const int t = wid * 5 + j;
    if (t >= NTloc) break;
    const int gn = ((tb + t) << 4) + cc;
    if (gn >= N) continue;
#pragma unroll
    for (int i = 0; i < 4; i++) {
#pragma unroll
      for (int r = 0; r < 4; r++) {
        const int gm = m0 + (i << 4) + cr + r;
        if (gm >= M) continue;
        const size_t rowoff = (size_t)gm * ldc;
        float v = acc[i][j][r];
        if constexpr (ADDMAT) v += D[rowoff + gn];
        if constexpr (BIAS) v += bias[gn];
        if constexpr (RELU) v = fmaxf(v, 0.f);
        C[rowoff + gn] = v;
        if constexpr (W2) C2[rowoff + gn] = v;
      }
    }
  }
}

// ============== neighbor aggregation (float4): sum * max over 6 ==============
template<bool UPDATE>
__global__ __launch_bounds__(256) void agg_kernel(
    const float* __restrict__ message_bond, const int* __restrict__ a2b,
    float* __restrict__ out)
{
  int gid = blockIdx.x * 256 + threadIdx.x;
  if (gid >= NAt * 75) return;
  int a = gid / 75;
  int c4 = gid - a * 75;
  const int* ab = a2b + (size_t)a * 6;
  float4 s = {0.f, 0.f, 0.f, 0.f};
  float4 mx = {-3.0e38f, -3.0e38f, -3.0e38f, -3.0e38f};
#pragma unroll
  for (int j = 0; j < 6; j++) {
    float4 v = *(const float4*)(message_bond + (size_t)ab[j] * H + c4 * 4);
    s.x += v.x; s.y += v.y; s.z += v.z; s.w += v.w;
    mx.x = fmaxf(mx.x, v.x); mx.y = fmaxf(mx.y, v.y);
    mx.z = fmaxf(mx.z, v.z); mx.w = fmaxf(mx.w, v.w);
  }
  float4* o = (float4*)(out + (size_t)a * H + c4 * 4);
  float4 r;
  r.x = s.x * mx.x; r.y = s.y * mx.y; r.z = s.z * mx.z; r.w = s.w * mx.w;
  if (UPDATE) {
    float4 c = *o;
    r.x += c.x; r.y += c.y; r.z += c.z; r.w += c.w;
  }
  *o = r;
}

// ======================= misc elementwise =======================
__global__ __launch_bounds__(256) void msg_kernel(
    const float* __restrict__ node, const float* __restrict__ gru_bias,
    float* __restrict__ msg)
{
  int gid = blockIdx.x * 256 + threadIdx.x;
  if (gid >= NAt * H) return;
  int hh = gid % H;
  msg[gid] = fmaxf(node[gid] + gru_bias[hh], 0.f);
}

__global__ __launch_bounds__(256) void h0_kernel(
    const float* __restrict__ node, float* __restrict__ h0)
{
  int gid = blockIdx.x * 256 + threadIdx.x;
  if (gid >= NM * H) return;
  int m = gid / H;
  int hh = gid - m * H;
  const float* base = node + ((size_t)(1 + m * APM)) * H + hh;
  float mx = base[0];
  for (int t = 1; t < APM; t++) mx = fmaxf(mx, base[(size_t)t * H]);
  h0[gid] = mx;
}

__global__ __launch_bounds__(256) void row0_kernel(
    const float* __restrict__ msg, float* __restrict__ message)
{
  int gid = blockIdx.x * 256 + threadIdx.x;
  if (gid >= 2 * H) return;
  message[gid] = msg[gid % H];
}

__global__ __launch_bounds__(256) void mean_kernel(
    const float* __restrict__ ah, float* __restrict__ out)
{
  int gid = blockIdx.x * 256 + threadIdx.x;
  if (gid >= NM * H) return;
  int m = gid / H;
  int hh = gid - m * H;
  const float* base = ah + ((size_t)(1 + m * APM)) * H + hh;
  float s = 0.f;
#pragma unroll 8
  for (int t = 0; t < APM; t++) s += base[(size_t)t * H];
  out[gid] = s * (1.f / APM);
}

// ======================= GRU step =======================
__global__ __launch_bounds__(256) void gru_step_kernel(
    const float* __restrict__ xg_f, const float* __restrict__ xg_b,
    const float* __restrict__ w_hh_f, const float* __restrict__ w_hh_b,
    const float* __restrict__ b_hh_f, const float* __restrict__ b_hh_b,
    const float* __restrict__ h0,
    float* __restrict__ h_buf,   // [2][2][NM][H]
    float* __restrict__ g_buf,   // [2][2][NM][H3]
    float* __restrict__ message, // [NAt][600]
    int s)
{
  __shared__ float h_lds[8 * H];
  const int tid = threadIdx.x;
  const int b = blockIdx.x;
  const int ct = b & 3;
  const int mg = (b >> 2) & 31;
  const int dir = b >> 7;
  const int r = s & 1;
  const int w = 1 - r;
  const float* xg = dir ? xg_b : xg_f;
  const float* whh = dir ? w_hh_b : w_hh_f;
  const float* bhh = dir ? b_hh_b : b_hh_f;
  const float* hb_r = h_buf + ((size_t)(r * 2 + dir)) * NM * H;
  float* hb_w = h_buf + ((size_t)(w * 2 + dir)) * NM * H;
  const float* gb_r = g_buf + ((size_t)(r * 2 + dir)) * NM * H3;
  float* gb_w = g_buf + ((size_t)(w * 2 + dir)) * NM * H3;

  int t_prev = 0;
  if (s > 0) t_prev = dir ? (64 - s) : (s - 1);

  // phase 1: h_cur for this block's 8 mols
  for (int i = tid; i < 8 * H; i += 256) {
    int m = i / H;
    int hh = i - m * H;
    int mol = mg * 8 + m;
    float hc;
    if (s == 0) {
      hc = h0[(size_t)mol * H + hh];
    } else {
      const float* xr = xg + ((size_t)(mol * 64 + t_prev)) * H3;
      float ir = xr[hh], iz = xr[H + hh], inn = xr[2 * H + hh];
      const float* gp = gb_r + (size_t)mol * H3;
      float hr = gp[hh], hz = gp[H + hh], hn = gp[2 * H + hh];
      float hp = hb_r[(size_t)mol * H + hh];
      float rr = 1.f / (1.f + expf(-(ir + hr)));
      float zz = 1.f / (1.f + expf(-(iz + hz)));
      float nn = tanhf(inn + rr * hn);
      hc = (1.f - zz) * nn + zz * hp;
    }
    h_lds[i] = hc;
    if (ct == 0) {
      hb_w[(size_t)mol * H + hh] = hc;
      if (s > 0) {
        int row = 1 + mol * 64 + t_prev;
        message[(size_t)row * 600 + dir * H + hh] = hc;
      }
    }
  }
  __syncthreads();
  if (s >= 64) return;

  // phase 2: gate slice [ct*225,(ct+1)*225), 2-way ILP
  for (int base = tid; base < 8 * 225; base += 512) {
    const int iA = base;
    const int iB = base + 256;
    const bool hasB = iB < 8 * 225;
    const int mA = iA & 7;
    const int gA = ct * 225 + (iA >> 3);
    const int mB = hasB ? (iB & 7) : mA;
    const int gB = hasB ? (ct * 225 + (iB >> 3)) : gA;
    const float4* wA = (const float4*)(whh + (size_t)gA * H);
    const float4* wB = (const float4*)(whh + (size_t)gB * H);
    const float4* hA = (const float4*)(h_lds + mA * H);
    const float4* hB = (const float4*)(h_lds + mB * H);
    float accA = bhh[gA];
    float accB = hasB ? bhh[gB] : 0.f;
#pragma unroll 5
    for (int k = 0; k < H / 4; k++) {
      float4 wa = wA[k], ha = hA[k];
      float4 wb = wB[k], hb = hB[k];
      accA += wa.x * ha.x + wa.y * ha.y + wa.z * ha.z + wa.w * ha.w;
      accB += wb.x * hb.x + wb.y * hb.y + wb.z * hb.z + wb.w * hb.w;
    }
    gb_w[(size_t)(mg * 8 + mA) * H3 + gA] = accA;
    if (hasB) gb_w[(size_t)(mg * 8 + mB) * H3 + gB] = accB;
  }
}

// ======================= host =======================
// Base layout 63,898,800 floats = 255.6 MB + pre-split weights 9.2 MB at tail.
extern "C" void kernel_launch(void* const* d_in, const int* in_sizes, int n_in,
                              void* d_out, int out_size, void* d_ws, size_t ws_size,
                              hipStream_t stream) {
  (void)in_sizes; (void)n_in; (void)out_size; (void)ws_size;
  const float* f_atoms  = (const float*)d_in[0];
  const float* f_bonds  = (const float*)d_in[1];
  const int*   a2b      = (const int*)d_in[2];
  const int*   b2a      = (const int*)d_in[3];
  const int*   b2revb   = (const int*)d_in[4];
  const float* W_i_atom = (const float*)d_in[5];
  const float* W_i_bond = (const float*)d_in[6];
  const float* W_h      = (const float*)d_in[7];
  const float* W_lr     = (const float*)d_in[8];
  const float* W_o      = (const float*)d_in[9];
  const float* b_o      = (const float*)d_in[10];
  const float* gru_bias = (const float*)d_in[11];
  const float* w_ih_f   = (const float*)d_in[12];
  const float* w_hh_f   = (const float*)d_in[13];
  const float* b_ih_f   = (const float*)d_in[14];
  const float* b_hh_f   = (const float*)d_in[15];
  const float* w_ih_b   = (const float*)d_in[16];
  const float* w_hh_b   = (const float*)d_in[17];
  const float* b_ih_b   = (const float*)d_in[18];
  const float* b_hh_b   = (const float*)d_in[19];

  float* ws = (float*)d_ws;
  const size_t SZ_B = (size_t)NBd * H;  // 19,661,100
  const size_t SZ_A = (size_t)NAt * H;  //  4,915,500

  float* ib  = ws;
  float* mb0 = ws + SZ_B;
  float* mb1 = ws + 2 * SZ_B;
  float* ma  = ws + 3 * SZ_B;
  float* xgf     = ib;
  float* message = mb0;
  float* h0      = mb0 + 9831000;
  float* hbuf    = h0 + (size_t)NM * H + 2 * (size_t)H * H3;
  float* gbuf    = hbuf + (size_t)4 * NM * H;
  float* aggb    = mb1;
  float* node    = mb1 + SZ_A;
  float* iat     = mb1 + 2 * SZ_A;
  float* msg     = mb1 + 14745600;
  float* xgb     = mb1;
  float* ah      = ma;

  // pre-split weight region at tail (uint4 granule counts)
  const size_t BASE_FLOATS = 63898800;
  uint4* wsp = (uint4*)(ws + BASE_FLOATS);
  const int G_IA = 5 * 19 * 64;
  const int G_IB = 5 * 19 * 64;
  const int G_WH = 10 * 19 * 64;
  const int G_LR = 29 * 19 * 64;
  const int G_WT = 10 * 57 * 64;
  const int G_WO = 19 * 19 * 64;
  uint4* sp_ia = wsp;
  uint4* sp_ib = sp_ia + 3 * G_IA;
  uint4* sp_wh = sp_ib + 3 * G_IB;
  uint4* sp_lr = sp_wh + 4 * 3 * G_WH;
  uint4* sp_tf = sp_lr + 3 * G_LR;
  uint4* sp_tb = sp_tf + 3 * G_WT;
  uint4* sp_wo = sp_tb + 3 * G_WT;

  dim3 blk(256);
  auto gg3 = [](int M, int NT) {
    return dim3((unsigned)((NT + 19) / 20), (unsigned)((M + 63) / 64));
  };
  auto pg = [](int gran) { return dim3((unsigned)((gran + 255) / 256)); };
  const int gA4 = (int)((NAt * 75 + 255) / 256);
  const int gAe = (int)((SZ_A + 255) / 256);

  // ---- weight prep ----
  prep_split_kernel<false><<<pg(G_IA), blk, 0, stream>>>(W_i_atom, sp_ia, 133, 300, 300, 5, 19);
  prep_split_kernel<false><<<pg(G_IB), blk, 0, stream>>>(W_i_bond, sp_ib, 147, 300, 300, 5, 19);
  for (int d = 0; d < 4; d++)
    prep_split_kernel<false><<<pg(G_WH), blk, 0, stream>>>(
        W_h + (size_t)d * H * H, sp_wh + (size_t)d * 3 * G_WH, 300, 300, 300, 10, 19);
  prep_split_kernel<false><<<pg(G_LR), blk, 0, stream>>>(W_lr, sp_lr, 900, 300, 300, 29, 19);
  prep_split_kernel<true><<<pg(G_WT), blk, 0, stream>>>(w_ih_f, sp_tf, 300, 900, 300, 10, 57);
  prep_split_kernel<true><<<pg(G_WT), blk, 0, stream>>>(w_ih_b, sp_tb, 300, 900, 300, 10, 57);
  prep_split_kernel<false><<<pg(G_WO), blk, 0, stream>>>(W_o, sp_wo, 600, 300, 300, 19, 19);

  // ma = relu(f_atoms @ W_i_atom)   (lda=133: scalar loads)
  gemm_mfma3<false,false,true,false,false,false,false><<<gg3(NAt, 19), blk, 0, stream>>>(
      f_atoms, nullptr, nullptr, nullptr, nullptr, sp_ia, ma, nullptr, nullptr, nullptr,
      NAt, H, 133, 133, H, 5, 19);
  // ib = relu(f_bonds @ W_i_bond); mb0 = copy   (lda=147: scalar loads)
  gemm_mfma3<false,false,true,false,false,true,false><<<gg3(NBd, 19), blk, 0, stream>>>(
      f_bonds, nullptr, nullptr, nullptr, nullptr, sp_ib, ib, mb0, nullptr, nullptr,
      NBd, H, 147, 147, H, 5, 19);

  float* mbp[2] = {mb0, mb1};
  int cur = 0;
  for (int d = 0; d < 4; d++) {
    agg_kernel<true><<<gA4, blk, 0, stream>>>(mbp[cur], a2b, ma);
    gemm_mfma3<true,false,true,true,false,false,true><<<gg3(NBd, 19), blk, 0, stream>>>(
        ma, mbp[cur], nullptr, b2a, b2revb, sp_wh + (size_t)d * 3 * G_WH,
        mbp[1 - cur], nullptr, ib, nullptr, NBd, H, H, H, H, 10, 19);
    cur ^= 1;
  }
  agg_kernel<false><<<gA4, blk, 0, stream>>>(mb0, a2b, aggb);

  gemm_mfma3<false,false,true,false,false,false,false><<<gg3(NAt, 19), blk, 0, stream>>>(
      f_atoms, nullptr, nullptr, nullptr, nullptr, sp_ia, iat, nullptr, nullptr, nullptr,
      NAt, H, 133, 133, H, 5, 19);
  gemm_mfma3<false,false,false,false,true,false,false><<<gg3(NAt, 19), blk, 0, stream>>>(
      aggb, ma, iat, nullptr, nullptr, sp_lr, node, nullptr, nullptr, nullptr,
      NAt, H, 900, H, H, 29, 19);

  h0_kernel<<<(NM * H + 255) / 256, blk, 0, stream>>>(node, h0);
  msg_kernel<<<gAe, blk, 0, stream>>>(node, gru_bias, msg);

  gemm_mfma3<false,true,false,false,false,false,true><<<gg3(16384, 57), blk, 0, stream>>>(
      msg + H, nullptr, nullptr, nullptr, nullptr, sp_tf, xgf, nullptr, nullptr, b_ih_f,
      16384, H3, H, H, H3, 10, 57);
  gemm_mfma3<false,true,false,false,false,false,true><<<gg3(16384, 57), blk, 0, stream>>>(
      msg + H, nullptr, nullptr, nullptr, nullptr, sp_tb, xgb, nullptr, nullptr, b_ih_b,
      16384, H3, H, H, H3, 10, 57);

  for (int s = 0; s <= 64; s++) {
    gru_step_kernel<<<256, blk, 0, stream>>>(
        xgf, xgb, w_hh_f, w_hh_b, b_hh_f, b_hh_b, h0, hbuf, gbuf, message, s);
  }
  row0_kernel<<<3, blk, 0, stream>>>(msg, message);

  gemm_mfma3<false,true,true,false,false,false,true><<<gg3(NAt, 19), blk, 0, stream>>>(
      message, nullptr, nullptr, nullptr, nullptr, sp_wo, ah, nullptr, nullptr, b_o,
      NAt, H, 600, 600, H, 19, 19);
  mean_kernel<<<(NM * H + 255) / 256, blk, 0, stream>>>(ah, (float*)d_out);
}

// Round 9
// 2964.095 us; speedup vs baseline: 1.9575x; 1.2223x over previous
//
#include <hip/hip_runtime.h>
#include <math.h>

#define H 300
#define H3 900
#define NAt 16385
#define NBd 65537
#define NM 256
#define APM 64

typedef __attribute__((ext_vector_type(8))) short bf16x8;
typedef __attribute__((ext_vector_type(4))) float f32x4;

__device__ __forceinline__ unsigned bf16_rne(float x) {
  unsigned u = __float_as_uint(x);
  return (u + 0x7fffu + ((u >> 16) & 1u)) >> 16;
}
__device__ __forceinline__ float bf16_up(unsigned h) {
  return __uint_as_float(h << 16);
}
// 3-way split: x ~= h + m + l (each bf16), residual ~2^-26 |x|
__device__ __forceinline__ void split3(float x, unsigned &h, unsigned &m, unsigned &l) {
  h = bf16_rne(x);
  float r1 = x - bf16_up(h);
  m = bf16_rne(r1);
  float r2 = r1 - bf16_up(m);
  l = bf16_rne(r2);
}
__device__ __forceinline__ void pack8(const unsigned* v, uint4 &o) {
  o.x = v[0] | (v[1] << 16); o.y = v[2] | (v[3] << 16);
  o.z = v[4] | (v[5] << 16); o.w = v[6] | (v[7] << 16);
}

// ======================= weight pre-split =======================
template<bool TRANS>
__global__ __launch_bounds__(256) void prep_split_kernel(
    const float* __restrict__ B, uint4* __restrict__ out,
    int K, int N, int ldb, int KT, int NT)
{
  int g = blockIdx.x * 256 + threadIdx.x;
  int total = KT * NT * 64;
  if (g >= total) return;
  int lane = g & 63;
  int t = (g >> 6) % NT;
  int kt = (g >> 6) / NT;
  int n = t * 16 + (lane & 15);
  int kb = kt * 32 + ((lane >> 4) << 3);
  float x[8];
#pragma unroll
  for (int j = 0; j < 8; j++) {
    int gk = kb + j;
    float v = 0.f;
    if (n < N && gk < K)
      v = TRANS ? B[(size_t)n * ldb + gk] : B[(size_t)gk * ldb + n];
    x[j] = v;
  }
  unsigned h[8], m[8], l[8];
#pragma unroll
  for (int j = 0; j < 8; j++) split3(x[j], h[j], m[j], l[j]);
  uint4 hv, mv, lv;
  pack8(h, hv); pack8(m, mv); pack8(l, lv);
  out[g] = hv;
  out[total + g] = mv;
  out[2 * total + g] = lv;
}

// ============== split-bf16 MFMA GEMM (r8 frozen: dwordx4 A loads, (256,3)) ==============
template<bool ADDMAT, bool BIAS, bool RELU, bool GATHER, bool CONCAT, bool W2, bool VEC>
__global__ __launch_bounds__(256, 3) void gemm_mfma3(
    const float* __restrict__ A, const float* __restrict__ A2,
    const float* __restrict__ A3,
    const int* __restrict__ idx1, const int* __restrict__ idx2,
    const uint4* __restrict__ Bs,
    float* __restrict__ C, float* __restrict__ C2,
    const float* __restrict__ D, const float* __restrict__ bias,
    int M, int N, int K, int lda, int ldc, int KT, int NT)
{
  __shared__ uint4 sA[2][3][256];
  const int tid = threadIdx.x;
  const int lane = tid & 63;
  const int wid = tid >> 6;
  const int m0 = blockIdx.y * 64;
  const int tb = blockIdx.x * 20;
  int NTloc = NT - tb;
  if (NTloc > 20) NTloc = 20;

  const int a_row = m0 + (wid << 4) + (lane & 15);
  const int a_koct = lane >> 4;
  const bool arok = a_row < M;
  const float* Ap = nullptr;
  const float* Ap2 = nullptr;
  const float* Ap3 = nullptr;
  if constexpr (GATHER) {
    int i1 = arok ? idx1[a_row] : 0;
    int i2 = arok ? idx2[a_row] : 0;
    Ap  = A  + (size_t)i1 * lda;
    Ap2 = A2 + (size_t)i2 * lda;
  } else if constexpr (CONCAT) {
    int r = arok ? a_row : 0;
    Ap  = A  + (size_t)r * lda;
    Ap2 = A2 + (size_t)r * lda;
    Ap3 = A3 + (size_t)r * lda;
  } else {
    Ap = A + (size_t)(arok ? a_row : 0) * lda;
  }

  const int PS = KT * NT * 64;  // plane stride (uint4 units)

  f32x4 acc[4][5];
#pragma unroll
  for (int i = 0; i < 4; i++)
#pragma unroll
    for (int j = 0; j < 5; j++) acc[i][j] = (f32x4){0.f, 0.f, 0.f, 0.f};

  float ax[8];
  auto loadA = [&](int kt_) {
    const int gk0 = (kt_ << 5) + (a_koct << 3);
    if constexpr (VEC && !CONCAT) {
      if (arok && gk0 + 8 <= K) {
        float4 p0 = *(const float4*)(Ap + gk0);
        float4 p1 = *(const float4*)(Ap + gk0 + 4);
        if constexpr (GATHER) {
          float4 q0 = *(const float4*)(Ap2 + gk0);
          float4 q1 = *(const float4*)(Ap2 + gk0 + 4);
          ax[0] = p0.x - q0.x; ax[1] = p0.y - q0.y;
          ax[2] = p0.z - q0.z; ax[3] = p0.w - q0.w;
          ax[4] = p1.x - q1.x; ax[5] = p1.y - q1.y;
          ax[6] = p1.z - q1.z; ax[7] = p1.w - q1.w;
        } else {
          ax[0] = p0.x; ax[1] = p0.y; ax[2] = p0.z; ax[3] = p0.w;
          ax[4] = p1.x; ax[5] = p1.y; ax[6] = p1.z; ax[7] = p1.w;
        }
        return;
      }
    }
#pragma unroll
    for (int j = 0; j < 8; j++) {
      int gk = gk0 + j;
      float v = 0.f;
      if (arok && gk < K) {
        if constexpr (GATHER) {
          v = Ap[gk] - Ap2[gk];
        } else if constexpr (CONCAT) {
          int s_ = (gk >= 2 * lda) ? 2 : ((gk >= lda) ? 1 : 0);
          int col = gk - s_ * lda;
          const float* src = (s_ == 0) ? Ap : ((s_ == 1) ? Ap2 : Ap3);
          v = src[col];
        } else {
          v = Ap[gk];
        }
      }
      ax[j] = v;
    }
  };
  auto writeA = [&](int slot) {
    unsigned h[8], m[8], l[8];
#pragma unroll
    for (int j = 0; j < 8; j++) split3(ax[j], h[j], m[j], l[j]);
    uint4 hv, mv, lv;
    pack8(h, hv); pack8(m, mv); pack8(l, lv);
    const int fi = (wid << 6) | lane;
    sA[slot][0][fi] = hv; sA[slot][1][fi] = mv; sA[slot][2][fi] = lv;
  };

  loadA(0);
  writeA(0);
  __syncthreads();

  for (int kt = 0; kt < KT; kt++) {
    const int cur = kt & 1;
    const bool more = kt + 1 < KT;
    if (more) loadA(kt + 1);

    bf16x8 aF[3][4];
#pragma unroll
    for (int p = 0; p < 3; p++)
#pragma unroll
      for (int i = 0; i < 4; i++)
        aF[p][i] = ((const bf16x8*)sA[cur][p])[(i << 6) | lane];
    const int bk = kt * NT * 64 + lane;
#pragma unroll
    for (int j = 0; j < 5; j++) {
      const int t = wid * 5 + j;
      if (t < NTloc) {
        const int gidx = bk + (tb + t) * 64;
        bf16x8 b0 = ((const bf16x8*)Bs)[gidx];
        bf16x8 b1 = ((const bf16x8*)Bs)[gidx + PS];
        bf16x8 b2 = ((const bf16x8*)Bs)[gidx + 2 * PS];
#pragma unroll
        for (int i = 0; i < 4; i++) {
          acc[i][j] = __builtin_amdgcn_mfma_f32_16x16x32_bf16(aF[2][i], b0, acc[i][j], 0, 0, 0);
          acc[i][j] = __builtin_amdgcn_mfma_f32_16x16x32_bf16(aF[0][i], b2, acc[i][j], 0, 0, 0);
          acc[i][j] = __builtin_amdgcn_mfma_f32_16x16x32_bf16(aF[1][i], b1, acc[i][j], 0, 0, 0);
          acc[i][j] = __builtin_amdgcn_mfma_f32_16x16x32_bf16(aF[1][i], b0, acc[i][j], 0, 0, 0);
          acc[i][j] = __builtin_amdgcn_mfma_f32_16x16x32_bf16(aF[0][i], b1, acc[i][j], 0, 0, 0);
          acc[i][j] = __builtin_amdgcn_mfma_f32_16x16x32_bf16(aF[0][i], b0, acc[i][j], 0, 0, 0);
        }
      }
    }
    if (more) writeA(cur ^ 1);
    __syncthreads();
  }

  // epilogue: C/D layout col=lane&15, row=(lane>>4)*4+r
  const int cr = (lane >> 4) << 2;
  const int cc = lane & 15;
#pragma unroll
  for (int j = 0; j < 5; j++) {
    const int t = wid * 5 + j;
    if (t >= NTloc) break;
    const int gn = ((tb + t) << 4) + cc;
    if (gn >= N) continue;
#pragma unroll
    for (int i = 0; i < 4; i++) {
#pragma unroll
      for (int r = 0; r < 4; r++) {
        const int gm = m0 + (i << 4) + cr + r;
        if (gm >= M) continue;
        const size_t rowoff = (size_t)gm * ldc;
        float v = acc[i][j][r];
        if constexpr (ADDMAT) v += D[rowoff + gn];
        if constexpr (BIAS) v += bias[gn];
        if constexpr (RELU) v = fmaxf(v, 0.f);
        C[rowoff + gn] = v;
        if constexpr (W2) C2[rowoff + gn] = v;
      }
    }
  }
}

// ============== neighbor aggregation (float4): sum * max over 6 ==============
template<bool UPDATE>
__global__ __launch_bounds__(256) void agg_kernel(
    const float* __restrict__ message_bond, const int* __restrict__ a2b,
    float* __restrict__ out)
{
  int gid = blockIdx.x * 256 + threadIdx.x;
  if (gid >= NAt * 75) return;
  int a = gid / 75;
  int c4 = gid - a * 75;
  const int* ab = a2b + (size_t)a * 6;
  float4 s = {0.f, 0.f, 0.f, 0.f};
  float4 mx = {-3.0e38f, -3.0e38f, -3.0e38f, -3.0e38f};
#pragma unroll
  for (int j = 0; j < 6; j++) {
    float4 v = *(const float4*)(message_bond + (size_t)ab[j] * H + c4 * 4);
    s.x += v.x; s.y += v.y; s.z += v.z; s.w += v.w;
    mx.x = fmaxf(mx.x, v.x); mx.y = fmaxf(mx.y, v.y);
    mx.z = fmaxf(mx.z, v.z); mx.w = fmaxf(mx.w, v.w);
  }
  float4* o = (float4*)(out + (size_t)a * H + c4 * 4);
  float4 r;
  r.x = s.x * mx.x; r.y = s.y * mx.y; r.z = s.z * mx.z; r.w = s.w * mx.w;
  if (UPDATE) {
    float4 c = *o;
    r.x += c.x; r.y += c.y; r.z += c.z; r.w += c.w;
  }
  *o = r;
}

// ======================= misc elementwise =======================
__global__ __launch_bounds__(256) void msg_kernel(
    const float* __restrict__ node, const float* __restrict__ gru_bias,
    float* __restrict__ msg)
{
  int gid = blockIdx.x * 256 + threadIdx.x;
  if (gid >= NAt * H) return;
  int hh = gid % H;
  msg[gid] = fmaxf(node[gid] + gru_bias[hh], 0.f);
}

__global__ __launch_bounds__(256) void h0_kernel(
    const float* __restrict__ node, float* __restrict__ h0)
{
  int gid = blockIdx.x * 256 + threadIdx.x;
  if (gid >= NM * H) return;
  int m = gid / H;
  int hh = gid - m * H;
  const float* base = node + ((size_t)(1 + m * APM)) * H + hh;
  float mx = base[0];
  for (int t = 1; t < APM; t++) mx = fmaxf(mx, base[(size_t)t * H]);
  h0[gid] = mx;
}

__global__ __launch_bounds__(256) void row0_kernel(
    const float* __restrict__ msg, float* __restrict__ message)
{
  int gid = blockIdx.x * 256 + threadIdx.x;
  if (gid >= 2 * H) return;
  message[gid] = msg[gid % H];
}

__global__ __launch_bounds__(256) void mean_kernel(
    const float* __restrict__ ah, float* __restrict__ out)
{
  int gid = blockIdx.x * 256 + threadIdx.x;
  if (gid >= NM * H) return;
  int m = gid / H;
  int hh = gid - m * H;
  const float* base = ah + ((size_t)(1 + m * APM)) * H + hh;
  float s = 0.f;
#pragma unroll 8
  for (int t = 0; t < APM; t++) s += base[(size_t)t * H];
  out[gid] = s * (1.f / APM);
}

// ======================= GRU step =======================
// phase 2 rewritten (r9): thread-per-gate, 8 mol-accumulators.
// W row loaded ONCE per gate (8x L2-traffic cut vs r8: 553 -> 69 MB/step);
// h read from LDS at wave-uniform addresses -> broadcast, conflict-free.
__global__ __launch_bounds__(256) void gru_step_kernel(
    const float* __restrict__ xg_f, const float* __restrict__ xg_b,
    const float* __restrict__ w_hh_f, const float* __restrict__ w_hh_b,
    const float* __restrict__ b_hh_f, const float* __restrict__ b_hh_b,
    const float* __restrict__ h0,
    float* __restrict__ h_buf,   // [2][2][NM][H]
    float* __restrict__ g_buf,   // [2][2][NM][H3]
    float* __restrict__ message, // [NAt][600]
    int s)
{
  __shared__ float h_lds[8 * H];
  const int tid = threadIdx.x;
  const int b = blockIdx.x;
  const int ct = b & 3;
  const int mg = (b >> 2) & 31;
  const int dir = b >> 7;
  const int r = s & 1;
  const int w = 1 - r;
  const float* xg = dir ? xg_b : xg_f;
  const float* whh = dir ? w_hh_b : w_hh_f;
  const float* bhh = dir ? b_hh_b : b_hh_f;
  const float* hb_r = h_buf + ((size_t)(r * 2 + dir)) * NM * H;
  float* hb_w = h_buf + ((size_t)(w * 2 + dir)) * NM * H;
  const float* gb_r = g_buf + ((size_t)(r * 2 + dir)) * NM * H3;
  float* gb_w = g_buf + ((size_t)(w * 2 + dir)) * NM * H3;

  int t_prev = 0;
  if (s > 0) t_prev = dir ? (64 - s) : (s - 1);

  // phase 1: h_cur for this block's 8 mols
  for (int i = tid; i < 8 * H; i += 256) {
    int m = i / H;
    int hh = i - m * H;
    int mol = mg * 8 + m;
    float hc;
    if (s == 0) {
      hc = h0[(size_t)mol * H + hh];
    } else {
      const float* xr = xg + ((size_t)(mol * 64 + t_prev)) * H3;
      float ir = xr[hh], iz = xr[H + hh], inn = xr[2 * H + hh];
      const float* gp = gb_r + (size_t)mol * H3;
      float hr = gp[hh], hz = gp[H + hh], hn = gp[2 * H + hh];
      float hp = hb_r[(size_t)mol * H + hh];
      float rr = 1.f / (1.f + expf(-(ir + hr)));
      float zz = 1.f / (1.f + expf(-(iz + hz)));
      float nn = tanhf(inn + rr * hn);
      hc = (1.f - zz) * nn + zz * hp;
    }
    h_lds[i] = hc;
    if (ct == 0) {
      hb_w[(size_t)mol * H + hh] = hc;
      if (s > 0) {
        int row = 1 + mol * 64 + t_prev;
        message[(size_t)row * 600 + dir * H + hh] = hc;
      }
    }
  }
  __syncthreads();
  if (s >= 64) return;

  // phase 2: thread t (<225) owns gate g = ct*225+t, computes all 8 mol dots.
  if (tid < 225) {
    const int g = ct * 225 + tid;
    const float4* wr = (const float4*)(whh + (size_t)g * H);
    float acc[8];
#pragma unroll
    for (int m = 0; m < 8; m++) acc[m] = 0.f;
    for (int k0 = 0; k0 < 75; k0 += 3) {
      float4 w0 = wr[k0];
      float4 w1 = wr[k0 + 1];
      float4 w2 = wr[k0 + 2];
#pragma unroll
      for (int m = 0; m < 8; m++) {
        const float4* hm = (const float4*)(h_lds + m * H);
        float4 a0 = hm[k0];
        float4 a1 = hm[k0 + 1];
        float4 a2 = hm[k0 + 2];
        acc[m] += w0.x * a0.x + w0.y * a0.y + w0.z * a0.z + w0.w * a0.w
                + w1.x * a1.x + w1.y * a1.y + w1.z * a1.z + w1.w * a1.w
                + w2.x * a2.x + w2.y * a2.y + w2.z * a2.z + w2.w * a2.w;
      }
    }
    const float bb = bhh[g];
#pragma unroll
    for (int m = 0; m < 8; m++)
      gb_w[(size_t)(mg * 8 + m) * H3 + g] = acc[m] + bb;
  }
}

// ======================= host =======================
// Base layout 63,898,800 floats = 255.6 MB + pre-split weights 9.2 MB at tail.
extern "C" void kernel_launch(void* const* d_in, const int* in_sizes, int n_in,
                              void* d_out, int out_size, void* d_ws, size_t ws_size,
                              hipStream_t stream) {
  (void)in_sizes; (void)n_in; (void)out_size; (void)ws_size;
  const float* f_atoms  = (const float*)d_in[0];
  const float* f_bonds  = (const float*)d_in[1];
  const int*   a2b      = (const int*)d_in[2];
  const int*   b2a      = (const int*)d_in[3];
  const int*   b2revb   = (const int*)d_in[4];
  const float* W_i_atom = (const float*)d_in[5];
  const float* W_i_bond = (const float*)d_in[6];
  const float* W_h      = (const float*)d_in[7];
  const float* W_lr     = (const float*)d_in[8];
  const float* W_o      = (const float*)d_in[9];
  const float* b_o      = (const float*)d_in[10];
  const float* gru_bias = (const float*)d_in[11];
  const float* w_ih_f   = (const float*)d_in[12];
  const float* w_hh_f   = (const float*)d_in[13];
  const float* b_ih_f   = (const float*)d_in[14];
  const float* b_hh_f   = (const float*)d_in[15];
  const float* w_ih_b   = (const float*)d_in[16];
  const float* w_hh_b   = (const float*)d_in[17];
  const float* b_ih_b   = (const float*)d_in[18];
  const float* b_hh_b   = (const float*)d_in[19];

  float* ws = (float*)d_ws;
  const size_t SZ_B = (size_t)NBd * H;  // 19,661,100
  const size_t SZ_A = (size_t)NAt * H;  //  4,915,500

  float* ib  = ws;
  float* mb0 = ws + SZ_B;
  float* mb1 = ws + 2 * SZ_B;
  float* ma  = ws + 3 * SZ_B;
  float* xgf     = ib;
  float* message = mb0;
  float* h0      = mb0 + 9831000;
  float* hbuf    = h0 + (size_t)NM * H + 2 * (size_t)H * H3;
  float* gbuf    = hbuf + (size_t)4 * NM * H;
  float* aggb    = mb1;
  float* node    = mb1 + SZ_A;
  float* iat     = mb1 + 2 * SZ_A;
  float* msg     = mb1 + 14745600;
  float* xgb     = mb1;
  float* ah      = ma;

  // pre-split weight region at tail (uint4 granule counts)
  const size_t BASE_FLOATS = 63898800;
  uint4* wsp = (uint4*)(ws + BASE_FLOATS);
  const int G_IA = 5 * 19 * 64;
  const int G_IB = 5 * 19 * 64;
  const int G_WH = 10 * 19 * 64;
  const int G_LR = 29 * 19 * 64;
  const int G_WT = 10 * 57 * 64;
  const int G_WO = 19 * 19 * 64;
  uint4* sp_ia = wsp;
  uint4* sp_ib = sp_ia + 3 * G_IA;
  uint4* sp_wh = sp_ib + 3 * G_IB;
  uint4* sp_lr = sp_wh + 4 * 3 * G_WH;
  uint4* sp_tf = sp_lr + 3 * G_LR;
  uint4* sp_tb = sp_tf + 3 * G_WT;
  uint4* sp_wo = sp_tb + 3 * G_WT;

  dim3 blk(256);
  auto gg3 = [](int M, int NT) {
    return dim3((unsigned)((NT + 19) / 20), (unsigned)((M + 63) / 64));
  };
  auto pg = [](int gran) { return dim3((unsigned)((gran + 255) / 256)); };
  const int gA4 = (int)((NAt * 75 + 255) / 256);
  const int gAe = (int)((SZ_A + 255) / 256);

  // ---- weight prep ----
  prep_split_kernel<false><<<pg(G_IA), blk, 0, stream>>>(W_i_atom, sp_ia, 133, 300, 300, 5, 19);
  prep_split_kernel<false><<<pg(G_IB), blk, 0, stream>>>(W_i_bond, sp_ib, 147, 300, 300, 5, 19);
  for (int d = 0; d < 4; d++)
    prep_split_kernel<false><<<pg(G_WH), blk, 0, stream>>>(
        W_h + (size_t)d * H * H, sp_wh + (size_t)d * 3 * G_WH, 300, 300, 300, 10, 19);
  prep_split_kernel<false><<<pg(G_LR), blk, 0, stream>>>(W_lr, sp_lr, 900, 300, 300, 29, 19);
  prep_split_kernel<true><<<pg(G_WT), blk, 0, stream>>>(w_ih_f, sp_tf, 300, 900, 300, 10, 57);
  prep_split_kernel<true><<<pg(G_WT), blk, 0, stream>>>(w_ih_b, sp_tb, 300, 900, 300, 10, 57);
  prep_split_kernel<false><<<pg(G_WO), blk, 0, stream>>>(W_o, sp_wo, 600, 300, 300, 19, 19);

  // ma = relu(f_atoms @ W_i_atom)
  gemm_mfma3<false,false,true,false,false,false,false><<<gg3(NAt, 19), blk, 0, stream>>>(
      f_atoms, nullptr, nullptr, nullptr, nullptr, sp_ia, ma, nullptr, nullptr, nullptr,
      NAt, H, 133, 133, H, 5, 19);
  // ib = relu(f_bonds @ W_i_bond); mb0 = copy
  gemm_mfma3<false,false,true,false,false,true,false><<<gg3(NBd, 19), blk, 0, stream>>>(
      f_bonds, nullptr, nullptr, nullptr, nullptr, sp_ib, ib, mb0, nullptr, nullptr,
      NBd, H, 147, 147, H, 5, 19);

  float* mbp[2] = {mb0, mb1};
  int cur = 0;
  for (int d = 0; d < 4; d++) {
    agg_kernel<true><<<gA4, blk, 0, stream>>>(mbp[cur], a2b, ma);
    gemm_mfma3<true,false,true,true,false,false,true><<<gg3(NBd, 19), blk, 0, stream>>>(
        ma, mbp[cur], nullptr, b2a, b2revb, sp_wh + (size_t)d * 3 * G_WH,
        mbp[1 - cur], nullptr, ib, nullptr, NBd, H, H, H, H, 10, 19);
    cur ^= 1;
  }
  agg_kernel<false><<<gA4, blk, 0, stream>>>(mb0, a2b, aggb);

  gemm_mfma3<false,false,true,false,false,false,false><<<gg3(NAt, 19), blk, 0, stream>>>(
      f_atoms, nullptr, nullptr, nullptr, nullptr, sp_ia, iat, nullptr, nullptr, nullptr,
      NAt, H, 133, 133, H, 5, 19);
  gemm_mfma3<false,false,false,false,true,false,false><<<gg3(NAt, 19), blk, 0, stream>>>(
      aggb, ma, iat, nullptr, nullptr, sp_lr, node, nullptr, nullptr, nullptr,
      NAt, H, 900, H, H, 29, 19);

  h0_kernel<<<(NM * H + 255) / 256, blk, 0, stream>>>(node, h0);
  msg_kernel<<<gAe, blk, 0, stream>>>(node, gru_bias, msg);

  gemm_mfma3<false,true,false,false,false,false,true><<<gg3(16384, 57), blk, 0, stream>>>(
      msg + H, nullptr, nullptr, nullptr, nullptr, sp_tf, xgf, nullptr, nullptr, b_ih_f,
      16384, H3, H, H, H3, 10, 57);
  gemm_mfma3<false,true,false,false,false,false,true><<<gg3(16384, 57), blk, 0, stream>>>(
      msg + H, nullptr, nullptr, nullptr, nullptr, sp_tb, xgb, nullptr, nullptr, b_ih_b,
      16384, H3, H, H, H3, 10, 57);

  for (int s = 0; s <= 64; s++) {
    gru_step_kernel<<<256, blk, 0, stream>>>(
        xgf, xgb, w_hh_f, w_hh_b, b_hh_f, b_hh_b, h0, hbuf, gbuf, message, s);
  }
  row0_kernel<<<3, blk, 0, stream>>>(msg, message);

  gemm_mfma3<false,true,true,false,false,false,true><<<gg3(NAt, 19), blk, 0, stream>>>(
      message, nullptr, nullptr, nullptr, nullptr, sp_wo, ah, nullptr, nullptr, b_o,
      NAt, H, 600, 600, H, 19, 19);
  mean_kernel<<<(NM * H + 255) / 256, blk, 0, stream>>>(ah, (float*)d_out);
}